// Round 1
// baseline (136.555 us; speedup 1.0000x reference)
//
#include <hip/hip_runtime.h>
#include <math.h>

#define Bb   64
#define Nn   8192
#define Dd   64
#define Cc   256
#define INn  128
#define CTRL 192
#define OUTW 320
#define EPSF 1e-8f

// ---------------- workspace layout (floats) ----------------
// k_w      : 0                (Bb*Dd = 4096)
// k_r      : 4096             (4096)
// erase    : 8192             (4096)
// add      : 12288            (4096)
// scal     : 16384            (Bb*8)  per-b: beta_w,g_w,gamma_w,knorm_w, beta_r,g_r,gamma_r,knorm_r
// svec     : 16896            (Bb*8)  per-b: s_w[0..2],pad, s_r[0..2],pad
// dots     : 17408            (Bb*Nn = 524288)
// nrmsq    : 541696           (524288)
// w_w      : 1065984          (524288)
// w_r      : 1590272          (524288)
// partials : 2114560          (2048*64 = 131072)
// total    : 2245632 floats ≈ 9.0 MiB
#define OFF_KW   0
#define OFF_KR   4096
#define OFF_ER   8192
#define OFF_AD   12288
#define OFF_SC   16384
#define OFF_SV   16896
#define OFF_DT   17408
#define OFF_NQ   541696
#define OFF_WW   1065984
#define OFF_WR   1590272
#define OFF_PT   2114560

__device__ __forceinline__ float softplusf(float x) {
    return (x > 20.f) ? x : log1pf(__expf(x));
}
__device__ __forceinline__ float sigmoidf(float x) {
    return 1.f / (1.f + __expf(-x));
}

// block = 256 threads (4 waves); red must hold 4 floats
__device__ __forceinline__ float blockSum256(float v, float* red) {
    #pragma unroll
    for (int m = 32; m >= 1; m >>= 1) v += __shfl_xor(v, m);
    __syncthreads();
    if ((threadIdx.x & 63) == 0) red[threadIdx.x >> 6] = v;
    __syncthreads();
    return red[0] + red[1] + red[2] + red[3];
}
__device__ __forceinline__ float blockMax256(float v, float* red) {
    #pragma unroll
    for (int m = 32; m >= 1; m >>= 1) v = fmaxf(v, __shfl_xor(v, m));
    __syncthreads();
    if ((threadIdx.x & 63) == 0) red[threadIdx.x >> 6] = v;
    __syncthreads();
    return fmaxf(fmaxf(red[0], red[1]), fmaxf(red[2], red[3]));
}

struct SetupArgs {
    const float *x, *prv, *Wc, *bc;
    const float *Wk_r, *bk_r, *Wb_r, *bb_r, *Wg_r, *bg_r, *Ws_r, *bs_r, *Wgam_r, *bgam_r;
    const float *Wk_w, *bk_w, *Wb_w, *bb_w, *Wg_w, *bg_w, *Ws_w, *bs_w, *Wgam_w, *bgam_w;
    const float *We_w, *be_w, *Wa_w, *ba_w;
    float *k_w, *k_r, *erase, *add, *scal, *svec, *out;
};

// one block per batch; computes h, all small projections + activations
__global__ __launch_bounds__(256) void k_setup(SetupArgs a) {
    __shared__ float ci[CTRL];
    __shared__ float h[Cc];
    __shared__ float kbuf[128];
    __shared__ float red[4];
    const int b = blockIdx.x, t = threadIdx.x;

    if (t < INn)       ci[t] = a.x[b * INn + t];
    else if (t < CTRL) ci[t] = a.prv[b * Dd + (t - INn)];
    __syncthreads();

    // h = relu(ctrl_in @ W_ctrl + b_ctrl)
    float acc = a.bc[t];
    for (int i = 0; i < CTRL; ++i) acc += ci[i] * a.Wc[i * Cc + t];
    float hv = fmaxf(acc, 0.f);
    h[t] = hv;
    a.out[b * OUTW + t] = hv;
    __syncthreads();

    // 4 D-wide projections: k_w, k_r, erase, add
    {
        const int job = t >> 6, d = t & 63;
        const float* W = (job == 0) ? a.Wk_w : (job == 1) ? a.Wk_r : (job == 2) ? a.We_w : a.Wa_w;
        const float* bs = (job == 0) ? a.bk_w : (job == 1) ? a.bk_r : (job == 2) ? a.be_w : a.ba_w;
        float p = bs[d];
        for (int c = 0; c < Cc; ++c) p += h[c] * W[c * Dd + d];
        if (job == 0)      { a.k_w[b * Dd + d] = p; kbuf[d] = p; }
        else if (job == 1) { a.k_r[b * Dd + d] = p; kbuf[64 + d] = p; }
        else if (job == 2) { a.erase[b * Dd + d] = sigmoidf(p); }
        else               { a.add[b * Dd + d] = tanhf(p); }
    }
    __syncthreads();

    // 12 scalar dot products over C
    float res[12];
    #pragma unroll
    for (int j = 0; j < 12; ++j) {
        const float* Wp; int stride;
        switch (j) {
            case 0: Wp = a.Wb_w;   stride = 1; break;
            case 1: Wp = a.Wg_w;   stride = 1; break;
            case 2: Wp = a.Wgam_w; stride = 1; break;
            case 3: case 4: case 5: Wp = a.Ws_w + (j - 3); stride = 3; break;
            case 6: Wp = a.Wb_r;   stride = 1; break;
            case 7: Wp = a.Wg_r;   stride = 1; break;
            case 8: Wp = a.Wgam_r; stride = 1; break;
            default: Wp = a.Ws_r + (j - 9); stride = 3; break;
        }
        res[j] = blockSum256(hv * Wp[t * stride], red);
    }
    float knw = blockSum256((t < 64) ? kbuf[t] * kbuf[t] : 0.f, red);
    float knr = blockSum256((t >= 64 && t < 128) ? kbuf[t] * kbuf[t] : 0.f, red);

    if (t == 0) {
        // write addressing scalars
        a.scal[b * 8 + 0] = softplusf(res[0] + a.bb_w[0]);
        a.scal[b * 8 + 1] = sigmoidf(res[1] + a.bg_w[0]);
        a.scal[b * 8 + 2] = softplusf(res[2] + a.bgam_w[0]) + 1.f;
        a.scal[b * 8 + 3] = sqrtf(knw);
        // read addressing scalars
        a.scal[b * 8 + 4] = softplusf(res[6] + a.bb_r[0]);
        a.scal[b * 8 + 5] = sigmoidf(res[7] + a.bg_r[0]);
        a.scal[b * 8 + 6] = softplusf(res[8] + a.bgam_r[0]) + 1.f;
        a.scal[b * 8 + 7] = sqrtf(knr);
        // shift softmaxes (3-way)
        {
            float v0 = res[3] + a.bs_w[0], v1 = res[4] + a.bs_w[1], v2 = res[5] + a.bs_w[2];
            float m = fmaxf(fmaxf(v0, v1), v2);
            float e0 = __expf(v0 - m), e1 = __expf(v1 - m), e2 = __expf(v2 - m);
            float s = e0 + e1 + e2;
            a.svec[b * 8 + 0] = e0 / s; a.svec[b * 8 + 1] = e1 / s; a.svec[b * 8 + 2] = e2 / s;
        }
        {
            float v0 = res[9] + a.bs_r[0], v1 = res[10] + a.bs_r[1], v2 = res[11] + a.bs_r[2];
            float m = fmaxf(fmaxf(v0, v1), v2);
            float e0 = __expf(v0 - m), e1 = __expf(v1 - m), e2 = __expf(v2 - m);
            float s = e0 + e1 + e2;
            a.svec[b * 8 + 4] = e0 / s; a.svec[b * 8 + 5] = e1 / s; a.svec[b * 8 + 6] = e2 / s;
        }
    }
}

// pass A: dots = mem . k_w, nrmsq = |mem|^2  (128 MiB streaming read)
__global__ __launch_bounds__(256) void k_dots(const float* __restrict__ mem,
                                              const float* __restrict__ kvec,
                                              float* __restrict__ dots,
                                              float* __restrict__ nrm) {
    const int lane = threadIdx.x & 63;
    const int gw = (blockIdx.x * blockDim.x + threadIdx.x) >> 6;
    const int nw = (gridDim.x * blockDim.x) >> 6;
    const int q = lane & 15, r = lane >> 4;
    const int totalGroups = (Bb * Nn) >> 2;
    for (int grp = gw; grp < totalGroups; grp += nw) {
        const int row = (grp << 2) + r;         // = b*N + n
        const int b = row >> 13;                // N = 8192
        const float4 mv = *(const float4*)(mem + ((size_t)row << 6) + (q << 2));
        const float4 kv = *(const float4*)(kvec + (b << 6) + (q << 2));
        float dot = mv.x * kv.x + mv.y * kv.y + mv.z * kv.z + mv.w * kv.w;
        float ns  = mv.x * mv.x + mv.y * mv.y + mv.z * mv.z + mv.w * mv.w;
        #pragma unroll
        for (int m = 8; m >= 1; m >>= 1) { dot += __shfl_xor(dot, m); ns += __shfl_xor(ns, m); }
        if (q == 0) { dots[row] = dot; nrm[row] = ns; }
    }
}

// pass B: recompute new_mem on the fly, dots_r = new_mem . k_r, nrmsq of new_mem
__global__ __launch_bounds__(256) void k_dots2(const float* __restrict__ mem,
                                               const float* __restrict__ kvec,
                                               const float* __restrict__ ww,
                                               const float* __restrict__ er,
                                               const float* __restrict__ ad,
                                               float* __restrict__ dots,
                                               float* __restrict__ nrm) {
    const int lane = threadIdx.x & 63;
    const int gw = (blockIdx.x * blockDim.x + threadIdx.x) >> 6;
    const int nw = (gridDim.x * blockDim.x) >> 6;
    const int q = lane & 15, r = lane >> 4;
    const int totalGroups = (Bb * Nn) >> 2;
    for (int grp = gw; grp < totalGroups; grp += nw) {
        const int row = (grp << 2) + r;
        const int b = row >> 13;
        const float4 mv = *(const float4*)(mem + ((size_t)row << 6) + (q << 2));
        const float4 kv = *(const float4*)(kvec + (b << 6) + (q << 2));
        const float4 ev = *(const float4*)(er + (b << 6) + (q << 2));
        const float4 av = *(const float4*)(ad + (b << 6) + (q << 2));
        const float w = ww[row];
        float4 nm;
        nm.x = mv.x * (1.f - w * ev.x) + w * av.x;
        nm.y = mv.y * (1.f - w * ev.y) + w * av.y;
        nm.z = mv.z * (1.f - w * ev.z) + w * av.z;
        nm.w = mv.w * (1.f - w * ev.w) + w * av.w;
        float dot = nm.x * kv.x + nm.y * kv.y + nm.z * kv.z + nm.w * kv.w;
        float ns  = nm.x * nm.x + nm.y * nm.y + nm.z * nm.z + nm.w * nm.w;
        #pragma unroll
        for (int m = 8; m >= 1; m >>= 1) { dot += __shfl_xor(dot, m); ns += __shfl_xor(ns, m); }
        if (q == 0) { dots[row] = dot; nrm[row] = ns; }
    }
}

// addressing finalize: sim -> softmax -> interpolate -> shift -> sharpen -> normalize
// one block per batch, N row in LDS
__global__ __launch_bounds__(256) void k_addr(const float* __restrict__ dots,
                                              const float* __restrict__ nrmsq,
                                              const float* __restrict__ prevw,
                                              const float* __restrict__ scal,
                                              const float* __restrict__ svec,
                                              float* __restrict__ wout,
                                              int which) {
    __shared__ float buf[Nn];
    __shared__ float red[4];
    const int b = blockIdx.x, t = threadIdx.x;
    const float beta  = scal[b * 8 + which * 4 + 0];
    const float g     = scal[b * 8 + which * 4 + 1];
    const float gam   = scal[b * 8 + which * 4 + 2];
    const float knorm = scal[b * 8 + which * 4 + 3];
    const float s0 = svec[b * 8 + which * 4 + 0];
    const float s1 = svec[b * 8 + which * 4 + 1];
    const float s2 = svec[b * 8 + which * 4 + 2];

    float xs[32];
    float lmax = -1e30f;
    #pragma unroll
    for (int i = 0; i < 32; ++i) {
        const int n = i * 256 + t;
        const float dv = dots[b * Nn + n];
        const float nq = nrmsq[b * Nn + n];
        const float sim = dv / (sqrtf(nq) * knorm + EPSF);
        const float xv = beta * sim;
        xs[i] = xv;
        lmax = fmaxf(lmax, xv);
    }
    const float M = blockMax256(lmax, red);
    float lsum = 0.f;
    #pragma unroll
    for (int i = 0; i < 32; ++i) { const float e = __expf(xs[i] - M); xs[i] = e; lsum += e; }
    const float S = blockSum256(lsum, red);
    const float inv = 1.f / S;
    #pragma unroll
    for (int i = 0; i < 32; ++i) {
        const int n = i * 256 + t;
        const float wc = xs[i] * inv;
        buf[n] = g * wc + (1.f - g) * prevw[b * Nn + n];
    }
    __syncthreads();
    float lps = 0.f;
    #pragma unroll
    for (int i = 0; i < 32; ++i) {
        const int n = i * 256 + t;
        // ws[i] = s0*wg[(i+1)%N] + s1*wg[i] + s2*wg[(i-1)%N]
        const float wsv = s0 * buf[(n + 1) & (Nn - 1)] + s1 * buf[n] + s2 * buf[(n - 1) & (Nn - 1)];
        const float wp = powf(wsv, gam);
        xs[i] = wp;
        lps += wp;
    }
    const float PS = blockSum256(lps, red);
    const float invp = 1.f / (PS + EPSF);
    #pragma unroll
    for (int i = 0; i < 32; ++i) wout[b * Nn + i * 256 + t] = xs[i] * invp;
}

// pass C: read_vec partials = sum_n new_mem[b,n,:] * w_r[b,n]; 32 blocks per batch
__global__ __launch_bounds__(256) void k_read(const float* __restrict__ mem,
                                              const float* __restrict__ ww,
                                              const float* __restrict__ er,
                                              const float* __restrict__ ad,
                                              const float* __restrict__ wr,
                                              float* __restrict__ partials) {
    __shared__ float lds[4 * 64];
    const int b = blockIdx.x >> 5;
    const int chunk = blockIdx.x & 31;
    const int t = threadIdx.x;
    const int lane = t & 63, wv = t >> 6;
    const int q = lane & 15, r = lane >> 4;
    const float4 ev = *(const float4*)(er + (b << 6) + (q << 2));
    const float4 av = *(const float4*)(ad + (b << 6) + (q << 2));
    float a0 = 0.f, a1 = 0.f, a2 = 0.f, a3 = 0.f;
    const int base_n = chunk << 8;
    for (int gi = wv; gi < 64; gi += 4) {
        const int n = base_n + (gi << 2) + r;
        const int row = b * Nn + n;
        const float4 mv = *(const float4*)(mem + ((size_t)row << 6) + (q << 2));
        const float w = ww[row];
        const float wrv = wr[row];
        const float nmx = mv.x * (1.f - w * ev.x) + w * av.x;
        const float nmy = mv.y * (1.f - w * ev.y) + w * av.y;
        const float nmz = mv.z * (1.f - w * ev.z) + w * av.z;
        const float nmw = mv.w * (1.f - w * ev.w) + w * av.w;
        a0 += nmx * wrv; a1 += nmy * wrv; a2 += nmz * wrv; a3 += nmw * wrv;
    }
    #pragma unroll
    for (int m = 16; m <= 32; m <<= 1) {
        a0 += __shfl_xor(a0, m); a1 += __shfl_xor(a1, m);
        a2 += __shfl_xor(a2, m); a3 += __shfl_xor(a3, m);
    }
    if (r == 0) {
        lds[wv * 64 + q * 4 + 0] = a0; lds[wv * 64 + q * 4 + 1] = a1;
        lds[wv * 64 + q * 4 + 2] = a2; lds[wv * 64 + q * 4 + 3] = a3;
    }
    __syncthreads();
    if (t < 64) {
        partials[blockIdx.x * 64 + t] = lds[t] + lds[64 + t] + lds[128 + t] + lds[192 + t];
    }
}

// deterministic final reduce of the 32 partials per (b,d) -> out[b,256+d]
__global__ __launch_bounds__(64) void k_reduce(const float* __restrict__ partials,
                                               float* __restrict__ out) {
    const int b = blockIdx.x, d = threadIdx.x;
    float s = 0.f;
    for (int i = 0; i < 32; ++i) s += partials[((b << 5) + i) * 64 + d];
    out[b * OUTW + 256 + d] = s;
}

extern "C" void kernel_launch(void* const* d_in, const int* in_sizes, int n_in,
                              void* d_out, int out_size, void* d_ws, size_t ws_size,
                              hipStream_t stream) {
    const float* x      = (const float*)d_in[0];
    const float* mem    = (const float*)d_in[1];
    const float* prw_r  = (const float*)d_in[2];   // prev_read_weights
    const float* prw_w  = (const float*)d_in[3];   // prev_write_weights
    const float* prv    = (const float*)d_in[4];   // prev_read_vector
    const float* Wc     = (const float*)d_in[5];
    const float* bc     = (const float*)d_in[6];
    const float* Wk_r   = (const float*)d_in[7];
    const float* bk_r   = (const float*)d_in[8];
    const float* Wb_r   = (const float*)d_in[9];
    const float* bb_r   = (const float*)d_in[10];
    const float* Wg_r   = (const float*)d_in[11];
    const float* bg_r   = (const float*)d_in[12];
    const float* Ws_r   = (const float*)d_in[13];
    const float* bs_r   = (const float*)d_in[14];
    const float* Wgam_r = (const float*)d_in[15];
    const float* bgam_r = (const float*)d_in[16];
    const float* Wk_w   = (const float*)d_in[17];
    const float* bk_w   = (const float*)d_in[18];
    const float* Wb_w   = (const float*)d_in[19];
    const float* bb_w   = (const float*)d_in[20];
    const float* Wg_w   = (const float*)d_in[21];
    const float* bg_w   = (const float*)d_in[22];
    const float* Ws_w   = (const float*)d_in[23];
    const float* bs_w   = (const float*)d_in[24];
    const float* Wgam_w = (const float*)d_in[25];
    const float* bgam_w = (const float*)d_in[26];
    const float* We_w   = (const float*)d_in[27];
    const float* be_w   = (const float*)d_in[28];
    const float* Wa_w   = (const float*)d_in[29];
    const float* ba_w   = (const float*)d_in[30];

    float* ws  = (float*)d_ws;
    float* out = (float*)d_out;

    SetupArgs a;
    a.x = x; a.prv = prv; a.Wc = Wc; a.bc = bc;
    a.Wk_r = Wk_r; a.bk_r = bk_r; a.Wb_r = Wb_r; a.bb_r = bb_r;
    a.Wg_r = Wg_r; a.bg_r = bg_r; a.Ws_r = Ws_r; a.bs_r = bs_r;
    a.Wgam_r = Wgam_r; a.bgam_r = bgam_r;
    a.Wk_w = Wk_w; a.bk_w = bk_w; a.Wb_w = Wb_w; a.bb_w = bb_w;
    a.Wg_w = Wg_w; a.bg_w = bg_w; a.Ws_w = Ws_w; a.bs_w = bs_w;
    a.Wgam_w = Wgam_w; a.bgam_w = bgam_w;
    a.We_w = We_w; a.be_w = be_w; a.Wa_w = Wa_w; a.ba_w = ba_w;
    a.k_w = ws + OFF_KW; a.k_r = ws + OFF_KR;
    a.erase = ws + OFF_ER; a.add = ws + OFF_AD;
    a.scal = ws + OFF_SC; a.svec = ws + OFF_SV; a.out = out;

    // 1) controller + small projections (also writes h into out[:,0:256])
    k_setup<<<Bb, 256, 0, stream>>>(a);
    // 2) write-addressing dots/norms over prev_memory
    k_dots<<<2048, 256, 0, stream>>>(mem, ws + OFF_KW, ws + OFF_DT, ws + OFF_NQ);
    // 3) finalize w_w
    k_addr<<<Bb, 256, 0, stream>>>(ws + OFF_DT, ws + OFF_NQ, prw_w,
                                   ws + OFF_SC, ws + OFF_SV, ws + OFF_WW, 0);
    // 4) read-addressing dots/norms over (recomputed) new_memory
    k_dots2<<<2048, 256, 0, stream>>>(mem, ws + OFF_KR, ws + OFF_WW,
                                      ws + OFF_ER, ws + OFF_AD,
                                      ws + OFF_DT, ws + OFF_NQ);
    // 5) finalize w_r
    k_addr<<<Bb, 256, 0, stream>>>(ws + OFF_DT, ws + OFF_NQ, prw_r,
                                   ws + OFF_SC, ws + OFF_SV, ws + OFF_WR, 1);
    // 6) read vector partials over (recomputed) new_memory
    k_read<<<Bb * 32, 256, 0, stream>>>(mem, ws + OFF_WW, ws + OFF_ER, ws + OFF_AD,
                                        ws + OFF_WR, ws + OFF_PT);
    // 7) deterministic final reduce -> out[:,256:320]
    k_reduce<<<Bb, 64, 0, stream>>>(ws + OFF_PT, out);
}

// Round 2
// 129.937 us; speedup vs baseline: 1.0509x; 1.0509x over previous
//
#include <hip/hip_runtime.h>
#include <math.h>

#define Bb   64
#define Nn   8192
#define Dd   64
#define Cc   256
#define INn  128
#define CTRL 192
#define OUTW 320
#define EPSF 1e-8f

// ---------------- workspace layout (floats) ----------------
#define OFF_DW 0                      // dots with k_w            [B*N]
#define OFF_NQ (OFF_DW + Bb*Nn)       // |mem|^2                  [B*N]
#define OFF_DR (OFF_NQ + Bb*Nn)       // dots with k_r            [B*N]
#define OFF_C1 (OFF_DR + Bb*Nn)       // sum m^2 e                [B*N]
#define OFF_C2 (OFF_C1 + Bb*Nn)       // sum m^2 e^2              [B*N]
#define OFF_C3 (OFF_C2 + Bb*Nn)       // sum m a                  [B*N]
#define OFF_C4 (OFF_C3 + Bb*Nn)       // sum m a e                [B*N]
#define OFF_C5 (OFF_C4 + Bb*Nn)       // sum m e k_r              [B*N]
#define OFF_WW (OFF_C5 + Bb*Nn)       // write weights            [B*N]
#define OFF_WR (OFF_WW + Bb*Nn)       // read weights             [B*N]
#define OFF_PT (OFF_WR + Bb*Nn)       // read-vec partials        [2048*64]
#define OFF_KW (OFF_PT + 2048*64)     // k_w                      [B*D]
#define OFF_KR (OFF_KW + Bb*Dd)       // k_r                      [B*D]
#define OFF_ER (OFF_KR + Bb*Dd)       // erase (post-sigmoid)     [B*D]
#define OFF_AD (OFF_ER + Bb*Dd)       // add (post-tanh)          [B*D]
#define OFF_SC (OFF_AD + Bb*Dd)       // per-b scalars            [B*16]
// per-b scalars: 0..3 beta_w,g_w,gam_w,knorm_w | 4..7 beta_r,g_r,gam_r,knorm_r
//                8..10 s_w | 11 AK=a.k_r | 12..14 s_r | 15 A2=|a|^2

__device__ __forceinline__ float softplusf(float x) {
    return (x > 20.f) ? x : log1pf(__expf(x));
}
__device__ __forceinline__ float sigmoidf(float x) {
    return 1.f / (1.f + __expf(-x));
}

// ---- block reductions for 1024 threads (16 waves), red[16] LDS ----
__device__ __forceinline__ float blockSum1024(float v, float* red) {
    #pragma unroll
    for (int m = 32; m >= 1; m >>= 1) v += __shfl_xor(v, m);
    __syncthreads();                         // protect red from prior use
    if ((threadIdx.x & 63) == 0) red[threadIdx.x >> 6] = v;
    __syncthreads();
    float s = 0.f;
    #pragma unroll
    for (int i = 0; i < 16; ++i) s += red[i];
    return s;
}
__device__ __forceinline__ float blockMax1024(float v, float* red) {
    #pragma unroll
    for (int m = 32; m >= 1; m >>= 1) v = fmaxf(v, __shfl_xor(v, m));
    __syncthreads();
    if ((threadIdx.x & 63) == 0) red[threadIdx.x >> 6] = v;
    __syncthreads();
    float s = -1e30f;
    #pragma unroll
    for (int i = 0; i < 16; ++i) s = fmaxf(s, red[i]);
    return s;
}

struct SetupArgs {
    const float *x, *prv, *Wc, *bc;
    const float *Wk_r, *bk_r, *Wb_r, *bb_r, *Wg_r, *bg_r, *Ws_r, *bs_r, *Wgam_r, *bgam_r;
    const float *Wk_w, *bk_w, *Wb_w, *bb_w, *Wg_w, *bg_w, *Ws_w, *bs_w, *Wgam_w, *bgam_w;
    const float *We_w, *be_w, *Wa_w, *ba_w;
    float *ws, *out;
};

// one block per batch: controller GEMM + all projections + batched scalar reductions
__global__ __launch_bounds__(256) void k_setup(SetupArgs a) {
    __shared__ float ci[CTRL];
    __shared__ float h[Cc];
    __shared__ float kbuf[128];
    __shared__ float abuf[64];
    __shared__ float red[4][16];
    __shared__ float sums[16];
    const int b = blockIdx.x, t = threadIdx.x;

    if (t < INn)       ci[t] = a.x[b * INn + t];
    else if (t < CTRL) ci[t] = a.prv[b * Dd + (t - INn)];
    __syncthreads();

    float acc = a.bc[t];
    #pragma unroll 4
    for (int i = 0; i < CTRL; ++i) acc += ci[i] * a.Wc[i * Cc + t];
    const float hv = fmaxf(acc, 0.f);
    h[t] = hv;
    a.out[b * OUTW + t] = hv;
    __syncthreads();

    {
        const int job = t >> 6, d = t & 63;
        const float* W  = (job == 0) ? a.Wk_w : (job == 1) ? a.Wk_r : (job == 2) ? a.We_w : a.Wa_w;
        const float* bs = (job == 0) ? a.bk_w : (job == 1) ? a.bk_r : (job == 2) ? a.be_w : a.ba_w;
        float p = bs[d];
        #pragma unroll 4
        for (int c = 0; c < Cc; ++c) p += h[c] * W[c * Dd + d];
        if (job == 0)      { a.ws[OFF_KW + b * Dd + d] = p; kbuf[d] = p; }
        else if (job == 1) { a.ws[OFF_KR + b * Dd + d] = p; kbuf[64 + d] = p; }
        else if (job == 2) { a.ws[OFF_ER + b * Dd + d] = sigmoidf(p); }
        else               { const float ad = tanhf(p); a.ws[OFF_AD + b * Dd + d] = ad; abuf[d] = ad; }
    }
    __syncthreads();

    // 16 batched reductions over the block
    float v[16];
    v[0] = hv * a.Wb_w[t];  v[1] = hv * a.Wg_w[t];  v[2] = hv * a.Wgam_w[t];
    v[3] = hv * a.Ws_w[t * 3 + 0]; v[4] = hv * a.Ws_w[t * 3 + 1]; v[5] = hv * a.Ws_w[t * 3 + 2];
    v[6] = hv * a.Wb_r[t];  v[7] = hv * a.Wg_r[t];  v[8] = hv * a.Wgam_r[t];
    v[9] = hv * a.Ws_r[t * 3 + 0]; v[10] = hv * a.Ws_r[t * 3 + 1]; v[11] = hv * a.Ws_r[t * 3 + 2];
    v[12] = (t < 64) ? kbuf[t] * kbuf[t] : 0.f;
    v[13] = (t >= 64 && t < 128) ? kbuf[t] * kbuf[t] : 0.f;
    v[14] = (t < 64) ? abuf[t] * kbuf[64 + t] : 0.f;
    v[15] = (t < 64) ? abuf[t] * abuf[t] : 0.f;
    #pragma unroll
    for (int k = 0; k < 16; ++k) {
        #pragma unroll
        for (int m = 32; m >= 1; m >>= 1) v[k] += __shfl_xor(v[k], m);
    }
    if ((t & 63) == 0) {
        #pragma unroll
        for (int k = 0; k < 16; ++k) red[t >> 6][k] = v[k];
    }
    __syncthreads();
    if (t < 16) sums[t] = red[0][t] + red[1][t] + red[2][t] + red[3][t];
    __syncthreads();

    if (t == 0) {
        float* sc = a.ws + OFF_SC + b * 16;
        sc[0] = softplusf(sums[0] + a.bb_w[0]);
        sc[1] = sigmoidf(sums[1] + a.bg_w[0]);
        sc[2] = softplusf(sums[2] + a.bgam_w[0]) + 1.f;
        sc[3] = sqrtf(sums[12]);
        sc[4] = softplusf(sums[6] + a.bb_r[0]);
        sc[5] = sigmoidf(sums[7] + a.bg_r[0]);
        sc[6] = softplusf(sums[8] + a.bgam_r[0]) + 1.f;
        sc[7] = sqrtf(sums[13]);
        {
            const float v0 = sums[3] + a.bs_w[0], v1 = sums[4] + a.bs_w[1], v2 = sums[5] + a.bs_w[2];
            const float m = fmaxf(fmaxf(v0, v1), v2);
            const float e0 = __expf(v0 - m), e1 = __expf(v1 - m), e2 = __expf(v2 - m);
            const float s = e0 + e1 + e2;
            sc[8] = e0 / s; sc[9] = e1 / s; sc[10] = e2 / s;
        }
        sc[11] = sums[14];
        {
            const float v0 = sums[9] + a.bs_r[0], v1 = sums[10] + a.bs_r[1], v2 = sums[11] + a.bs_r[2];
            const float m = fmaxf(fmaxf(v0, v1), v2);
            const float e0 = __expf(v0 - m), e1 = __expf(v1 - m), e2 = __expf(v2 - m);
            const float s = e0 + e1 + e2;
            sc[12] = e0 / s; sc[13] = e1 / s; sc[14] = e2 / s;
        }
        sc[15] = sums[15];
    }
}

// single streaming pass over mem: 8 per-row scalars
__global__ __launch_bounds__(256) void k_pass1(const float* __restrict__ mem,
                                               float* __restrict__ ws) {
    const int w    = (blockIdx.x * 256 + threadIdx.x) >> 6;   // wave 0..8191
    const int lane = threadIdx.x & 63;
    const int q = lane & 15, r = lane >> 4;
    const int wbase = w << 6;                                  // 64 rows per wave
    const int b = wbase >> 13;
    const float4 kw = *(const float4*)(ws + OFF_KW + (b << 6) + (q << 2));
    const float4 kr = *(const float4*)(ws + OFF_KR + (b << 6) + (q << 2));
    const float4 ev = *(const float4*)(ws + OFF_ER + (b << 6) + (q << 2));
    const float4 av = *(const float4*)(ws + OFF_AD + (b << 6) + (q << 2));
    float4 ekr; ekr.x = ev.x * kr.x; ekr.y = ev.y * kr.y; ekr.z = ev.z * kr.z; ekr.w = ev.w * kr.w;

    for (int it = 0; it < 16; ++it) {
        const int row = wbase + (it << 2) + r;
        const float4 m = *(const float4*)(mem + ((size_t)row << 6) + (q << 2));
        float dw, nq, dr, c1, c2, c3, c4, c5;
        {   // x
            const float mm = m.x * m.x, tt = mm * ev.x, ma = m.x * av.x;
            dw = m.x * kw.x; nq = mm; dr = m.x * kr.x;
            c1 = tt; c2 = tt * ev.x; c3 = ma; c4 = ma * ev.x; c5 = m.x * ekr.x;
        }
        {   // y
            const float mm = m.y * m.y, tt = mm * ev.y, ma = m.y * av.y;
            dw = fmaf(m.y, kw.y, dw); nq += mm; dr = fmaf(m.y, kr.y, dr);
            c1 += tt; c2 = fmaf(tt, ev.y, c2); c3 += ma; c4 = fmaf(ma, ev.y, c4); c5 = fmaf(m.y, ekr.y, c5);
        }
        {   // z
            const float mm = m.z * m.z, tt = mm * ev.z, ma = m.z * av.z;
            dw = fmaf(m.z, kw.z, dw); nq += mm; dr = fmaf(m.z, kr.z, dr);
            c1 += tt; c2 = fmaf(tt, ev.z, c2); c3 += ma; c4 = fmaf(ma, ev.z, c4); c5 = fmaf(m.z, ekr.z, c5);
        }
        {   // w
            const float mm = m.w * m.w, tt = mm * ev.w, ma = m.w * av.w;
            dw = fmaf(m.w, kw.w, dw); nq += mm; dr = fmaf(m.w, kr.w, dr);
            c1 += tt; c2 = fmaf(tt, ev.w, c2); c3 += ma; c4 = fmaf(ma, ev.w, c4); c5 = fmaf(m.w, ekr.w, c5);
        }
        #pragma unroll
        for (int mk = 8; mk >= 1; mk >>= 1) {
            dw += __shfl_xor(dw, mk); nq += __shfl_xor(nq, mk);
            dr += __shfl_xor(dr, mk); c1 += __shfl_xor(c1, mk);
            c2 += __shfl_xor(c2, mk); c3 += __shfl_xor(c3, mk);
            c4 += __shfl_xor(c4, mk); c5 += __shfl_xor(c5, mk);
        }
        if (q == 0) {
            ws[OFF_DW + row] = dw; ws[OFF_NQ + row] = nq; ws[OFF_DR + row] = dr;
            ws[OFF_C1 + row] = c1; ws[OFF_C2 + row] = c2; ws[OFF_C3 + row] = c3;
            ws[OFF_C4 + row] = c4; ws[OFF_C5 + row] = c5;
        }
    }
}

// write-addressing finalize: one block (1024 thr) per batch
__global__ __launch_bounds__(1024) void k_addrW(float* __restrict__ ws,
                                                const float* __restrict__ prevw) {
    __shared__ float buf[Nn];
    __shared__ float red[16];
    const int b = blockIdx.x, t = threadIdx.x;
    const int bN = b * Nn;
    const float beta = ws[OFF_SC + b * 16 + 0];
    const float g    = ws[OFF_SC + b * 16 + 1];
    const float gam  = ws[OFF_SC + b * 16 + 2];
    const float kn   = ws[OFF_SC + b * 16 + 3];
    const float s0   = ws[OFF_SC + b * 16 + 8];
    const float s1   = ws[OFF_SC + b * 16 + 9];
    const float s2   = ws[OFF_SC + b * 16 + 10];

    float xs[8];
    float lmax = -1e30f;
    #pragma unroll
    for (int i = 0; i < 8; ++i) {
        const int n = (i << 10) + t;
        const float d  = ws[OFF_DW + bN + n];
        const float qq = ws[OFF_NQ + bN + n];
        const float x = beta * d / (sqrtf(qq) * kn + EPSF);
        xs[i] = x; lmax = fmaxf(lmax, x);
    }
    const float M = blockMax1024(lmax, red);
    float lsum = 0.f;
    #pragma unroll
    for (int i = 0; i < 8; ++i) { const float e = __expf(xs[i] - M); xs[i] = e; lsum += e; }
    const float S = blockSum1024(lsum, red);
    const float sinv = 1.f / S;
    #pragma unroll
    for (int i = 0; i < 8; ++i) {
        const int n = (i << 10) + t;
        buf[n] = g * xs[i] * sinv + (1.f - g) * prevw[bN + n];
    }
    __syncthreads();
    float lps = 0.f;
    #pragma unroll
    for (int i = 0; i < 8; ++i) {
        const int n = (i << 10) + t;
        const float wsv = s0 * buf[(n + 1) & (Nn - 1)] + s1 * buf[n] + s2 * buf[(n - 1) & (Nn - 1)];
        const float wp = __expf(gam * __logf(wsv));
        xs[i] = wp; lps += wp;
    }
    const float PS = blockSum1024(lps, red);
    const float pinv = 1.f / (PS + EPSF);
    #pragma unroll
    for (int i = 0; i < 8; ++i) ws[OFF_WW + bN + (i << 10) + t] = xs[i] * pinv;
}

// read-addressing finalize via algebraic expansion (no mem re-read)
__global__ __launch_bounds__(1024) void k_addrR(float* __restrict__ ws,
                                                const float* __restrict__ prevw) {
    __shared__ float buf[Nn];
    __shared__ float red[16];
    const int b = blockIdx.x, t = threadIdx.x;
    const int bN = b * Nn;
    const float beta = ws[OFF_SC + b * 16 + 4];
    const float g    = ws[OFF_SC + b * 16 + 5];
    const float gam  = ws[OFF_SC + b * 16 + 6];
    const float kn   = ws[OFF_SC + b * 16 + 7];
    const float AK   = ws[OFF_SC + b * 16 + 11];
    const float s0   = ws[OFF_SC + b * 16 + 12];
    const float s1   = ws[OFF_SC + b * 16 + 13];
    const float s2   = ws[OFF_SC + b * 16 + 14];
    const float A2   = ws[OFF_SC + b * 16 + 15];

    float xs[8];
    float lmax = -1e30f;
    #pragma unroll
    for (int i = 0; i < 8; ++i) {
        const int n = (i << 10) + t;
        const float wv = ws[OFF_WW + bN + n];
        const float d  = ws[OFF_DR + bN + n] + wv * (AK - ws[OFF_C5 + bN + n]);
        float qq = ws[OFF_NQ + bN + n]
                 + 2.f * wv * (ws[OFF_C3 + bN + n] - ws[OFF_C1 + bN + n])
                 + wv * wv * (ws[OFF_C2 + bN + n] - 2.f * ws[OFF_C4 + bN + n] + A2);
        qq = fmaxf(qq, 0.f);
        const float x = beta * d / (sqrtf(qq) * kn + EPSF);
        xs[i] = x; lmax = fmaxf(lmax, x);
    }
    const float M = blockMax1024(lmax, red);
    float lsum = 0.f;
    #pragma unroll
    for (int i = 0; i < 8; ++i) { const float e = __expf(xs[i] - M); xs[i] = e; lsum += e; }
    const float S = blockSum1024(lsum, red);
    const float sinv = 1.f / S;
    #pragma unroll
    for (int i = 0; i < 8; ++i) {
        const int n = (i << 10) + t;
        buf[n] = g * xs[i] * sinv + (1.f - g) * prevw[bN + n];
    }
    __syncthreads();
    float lps = 0.f;
    #pragma unroll
    for (int i = 0; i < 8; ++i) {
        const int n = (i << 10) + t;
        const float wsv = s0 * buf[(n + 1) & (Nn - 1)] + s1 * buf[n] + s2 * buf[(n - 1) & (Nn - 1)];
        const float wp = __expf(gam * __logf(wsv));
        xs[i] = wp; lps += wp;
    }
    const float PS = blockSum1024(lps, red);
    const float pinv = 1.f / (PS + EPSF);
    #pragma unroll
    for (int i = 0; i < 8; ++i) ws[OFF_WR + bN + (i << 10) + t] = xs[i] * pinv;
}

// read-vector partials: recompute new_mem on the fly (second & last mem pass)
__global__ __launch_bounds__(256) void k_read(const float* __restrict__ mem,
                                              float* __restrict__ ws) {
    __shared__ float lds[4 * 64];
    const int b = blockIdx.x >> 5;
    const int chunk = blockIdx.x & 31;
    const int t = threadIdx.x;
    const int lane = t & 63, wv = t >> 6;
    const int q = lane & 15, r = lane >> 4;
    const float4 evv = *(const float4*)(ws + OFF_ER + (b << 6) + (q << 2));
    const float4 avv = *(const float4*)(ws + OFF_AD + (b << 6) + (q << 2));
    float a0 = 0.f, a1 = 0.f, a2 = 0.f, a3 = 0.f;
    const int base_n = chunk << 8;
    for (int gi = wv; gi < 64; gi += 4) {
        const int n = base_n + (gi << 2) + r;
        const int row = b * Nn + n;
        const float4 mv = *(const float4*)(mem + ((size_t)row << 6) + (q << 2));
        const float w   = ws[OFF_WW + row];
        const float wrv = ws[OFF_WR + row];
        a0 = fmaf((mv.x * (1.f - w * evv.x) + w * avv.x), wrv, a0);
        a1 = fmaf((mv.y * (1.f - w * evv.y) + w * avv.y), wrv, a1);
        a2 = fmaf((mv.z * (1.f - w * evv.z) + w * avv.z), wrv, a2);
        a3 = fmaf((mv.w * (1.f - w * evv.w) + w * avv.w), wrv, a3);
    }
    #pragma unroll
    for (int m = 16; m <= 32; m <<= 1) {
        a0 += __shfl_xor(a0, m); a1 += __shfl_xor(a1, m);
        a2 += __shfl_xor(a2, m); a3 += __shfl_xor(a3, m);
    }
    if (r == 0) {
        lds[wv * 64 + q * 4 + 0] = a0; lds[wv * 64 + q * 4 + 1] = a1;
        lds[wv * 64 + q * 4 + 2] = a2; lds[wv * 64 + q * 4 + 3] = a3;
    }
    __syncthreads();
    if (t < 64) {
        ws[OFF_PT + blockIdx.x * 64 + t] = lds[t] + lds[64 + t] + lds[128 + t] + lds[192 + t];
    }
}

__global__ __launch_bounds__(64) void k_reduce(const float* __restrict__ ws,
                                               float* __restrict__ out) {
    const int b = blockIdx.x, d = threadIdx.x;
    float s = 0.f;
    for (int i = 0; i < 32; ++i) s += ws[OFF_PT + ((b << 5) + i) * 64 + d];
    out[b * OUTW + 256 + d] = s;
}

extern "C" void kernel_launch(void* const* d_in, const int* in_sizes, int n_in,
                              void* d_out, int out_size, void* d_ws, size_t ws_size,
                              hipStream_t stream) {
    const float* x      = (const float*)d_in[0];
    const float* mem    = (const float*)d_in[1];
    const float* prw_r  = (const float*)d_in[2];
    const float* prw_w  = (const float*)d_in[3];
    const float* prv    = (const float*)d_in[4];

    float* ws  = (float*)d_ws;
    float* out = (float*)d_out;

    SetupArgs a;
    a.x = x; a.prv = prv;
    a.Wc = (const float*)d_in[5];  a.bc = (const float*)d_in[6];
    a.Wk_r = (const float*)d_in[7];  a.bk_r = (const float*)d_in[8];
    a.Wb_r = (const float*)d_in[9];  a.bb_r = (const float*)d_in[10];
    a.Wg_r = (const float*)d_in[11]; a.bg_r = (const float*)d_in[12];
    a.Ws_r = (const float*)d_in[13]; a.bs_r = (const float*)d_in[14];
    a.Wgam_r = (const float*)d_in[15]; a.bgam_r = (const float*)d_in[16];
    a.Wk_w = (const float*)d_in[17]; a.bk_w = (const float*)d_in[18];
    a.Wb_w = (const float*)d_in[19]; a.bb_w = (const float*)d_in[20];
    a.Wg_w = (const float*)d_in[21]; a.bg_w = (const float*)d_in[22];
    a.Ws_w = (const float*)d_in[23]; a.bs_w = (const float*)d_in[24];
    a.Wgam_w = (const float*)d_in[25]; a.bgam_w = (const float*)d_in[26];
    a.We_w = (const float*)d_in[27]; a.be_w = (const float*)d_in[28];
    a.Wa_w = (const float*)d_in[29]; a.ba_w = (const float*)d_in[30];
    a.ws = ws; a.out = out;

    k_setup<<<Bb, 256, 0, stream>>>(a);
    k_pass1<<<2048, 256, 0, stream>>>(mem, ws);
    k_addrW<<<Bb, 1024, 0, stream>>>(ws, prw_w);
    k_addrR<<<Bb, 1024, 0, stream>>>(ws, prw_r);
    k_read<<<Bb * 32, 256, 0, stream>>>(mem, ws);
    k_reduce<<<Bb, 64, 0, stream>>>(ws, out);
}

// Round 3
// 115.109 us; speedup vs baseline: 1.1863x; 1.1288x over previous
//
#include <hip/hip_runtime.h>
#include <math.h>

#define Bb   64
#define Nn   8192
#define Dd   64
#define Cc   256
#define INn  128
#define CTRL 192
#define OUTW 320
#define EPSF 1e-8f
#define BN   (Bb*Nn)

// ---------------- workspace layout (floats) ----------------
#define OFF_XW 0                      // beta_w * sim_w           [B*N]
#define OFF_DR (1*BN)                 // mem . k_r                [B*N]
#define OFF_C5 (2*BN)                 // sum m e k_r              [B*N]
#define OFF_NQ (3*BN)                 // |mem|^2                  [B*N]
#define OFF_E1 (4*BN)                 // sum(ma - m^2 e)          [B*N]
#define OFF_E2 (5*BN)                 // sum(m^2e^2 - 2mae)       [B*N]
#define OFF_WW (6*BN)                 // write weights            [B*N]
#define OFF_WR (7*BN)                 // read weights             [B*N]
#define OFF_PT (8*BN)                 // read-vec partials        [2048*64]
#define OFF_BM (OFF_PT + 2048*64)     // per-block max of x_w     [2048]
#define OFF_KW (OFF_BM + 2048)        // k_w                      [B*D]
#define OFF_KR (OFF_KW + Bb*Dd)       // k_r                      [B*D]
#define OFF_ER (OFF_KR + Bb*Dd)       // erase (post-sigmoid)     [B*D]
#define OFF_AD (OFF_ER + Bb*Dd)       // add (post-tanh)          [B*D]
#define OFF_SC (OFF_AD + Bb*Dd)       // per-b scalars            [B*16]
// per-b scalars: 0..3 beta_w,g_w,gam_w,knorm_w | 4..7 beta_r,g_r,gam_r,knorm_r
//                8..10 s_w | 11 AK=a.k_r | 12..14 s_r | 15 A2=|a|^2

__device__ __forceinline__ float softplusf(float x) {
    return (x > 20.f) ? x : log1pf(__expf(x));
}
__device__ __forceinline__ float sigmoidf(float x) {
    return 1.f / (1.f + __expf(-x));
}

// ---- block reductions for 1024 threads (16 waves), red[16] LDS ----
__device__ __forceinline__ float blockSum1024(float v, float* red) {
    #pragma unroll
    for (int m = 32; m >= 1; m >>= 1) v += __shfl_xor(v, m);
    __syncthreads();
    if ((threadIdx.x & 63) == 0) red[threadIdx.x >> 6] = v;
    __syncthreads();
    float s = 0.f;
    #pragma unroll
    for (int i = 0; i < 16; ++i) s += red[i];
    return s;
}
__device__ __forceinline__ float blockMax1024(float v, float* red) {
    #pragma unroll
    for (int m = 32; m >= 1; m >>= 1) v = fmaxf(v, __shfl_xor(v, m));
    __syncthreads();
    if ((threadIdx.x & 63) == 0) red[threadIdx.x >> 6] = v;
    __syncthreads();
    float s = -1e30f;
    #pragma unroll
    for (int i = 0; i < 16; ++i) s = fmaxf(s, red[i]);
    return s;
}

struct SetupArgs {
    const float *x, *prv, *Wc, *bc;
    const float *Wk_r, *bk_r, *Wb_r, *bb_r, *Wg_r, *bg_r, *Ws_r, *bs_r, *Wgam_r, *bgam_r;
    const float *Wk_w, *bk_w, *Wb_w, *bb_w, *Wg_w, *bg_w, *Ws_w, *bs_w, *Wgam_w, *bgam_w;
    const float *We_w, *be_w, *Wa_w, *ba_w;
    float *ws, *out;
};

// one block per batch: controller GEMM + projections + batched scalar reductions
__global__ __launch_bounds__(256) void k_setup(SetupArgs a) {
    __shared__ float ci[CTRL];
    __shared__ float h[Cc];
    __shared__ float kbuf[128];
    __shared__ float abuf[64];
    __shared__ float red[4][16];
    __shared__ float sums[16];
    const int b = blockIdx.x, t = threadIdx.x;

    if (t < INn)       ci[t] = a.x[b * INn + t];
    else if (t < CTRL) ci[t] = a.prv[b * Dd + (t - INn)];
    __syncthreads();

    float acc = a.bc[t];
    #pragma unroll 4
    for (int i = 0; i < CTRL; ++i) acc += ci[i] * a.Wc[i * Cc + t];
    const float hv = fmaxf(acc, 0.f);
    h[t] = hv;
    a.out[b * OUTW + t] = hv;
    __syncthreads();

    {
        const int job = t >> 6, d = t & 63;
        const float* W  = (job == 0) ? a.Wk_w : (job == 1) ? a.Wk_r : (job == 2) ? a.We_w : a.Wa_w;
        const float* bs = (job == 0) ? a.bk_w : (job == 1) ? a.bk_r : (job == 2) ? a.be_w : a.ba_w;
        float p = bs[d];
        #pragma unroll 4
        for (int c = 0; c < Cc; ++c) p += h[c] * W[c * Dd + d];
        if (job == 0)      { a.ws[OFF_KW + b * Dd + d] = p; kbuf[d] = p; }
        else if (job == 1) { a.ws[OFF_KR + b * Dd + d] = p; kbuf[64 + d] = p; }
        else if (job == 2) { a.ws[OFF_ER + b * Dd + d] = sigmoidf(p); }
        else               { const float ad = tanhf(p); a.ws[OFF_AD + b * Dd + d] = ad; abuf[d] = ad; }
    }
    __syncthreads();

    float v[16];
    v[0] = hv * a.Wb_w[t];  v[1] = hv * a.Wg_w[t];  v[2] = hv * a.Wgam_w[t];
    v[3] = hv * a.Ws_w[t * 3 + 0]; v[4] = hv * a.Ws_w[t * 3 + 1]; v[5] = hv * a.Ws_w[t * 3 + 2];
    v[6] = hv * a.Wb_r[t];  v[7] = hv * a.Wg_r[t];  v[8] = hv * a.Wgam_r[t];
    v[9] = hv * a.Ws_r[t * 3 + 0]; v[10] = hv * a.Ws_r[t * 3 + 1]; v[11] = hv * a.Ws_r[t * 3 + 2];
    v[12] = (t < 64) ? kbuf[t] * kbuf[t] : 0.f;
    v[13] = (t >= 64 && t < 128) ? kbuf[t] * kbuf[t] : 0.f;
    v[14] = (t < 64) ? abuf[t] * kbuf[64 + t] : 0.f;
    v[15] = (t < 64) ? abuf[t] * abuf[t] : 0.f;
    #pragma unroll
    for (int k = 0; k < 16; ++k) {
        #pragma unroll
        for (int m = 32; m >= 1; m >>= 1) v[k] += __shfl_xor(v[k], m);
    }
    if ((t & 63) == 0) {
        #pragma unroll
        for (int k = 0; k < 16; ++k) red[t >> 6][k] = v[k];
    }
    __syncthreads();
    if (t < 16) sums[t] = red[0][t] + red[1][t] + red[2][t] + red[3][t];
    __syncthreads();

    if (t == 0) {
        float* sc = a.ws + OFF_SC + b * 16;
        sc[0] = softplusf(sums[0] + a.bb_w[0]);
        sc[1] = sigmoidf(sums[1] + a.bg_w[0]);
        sc[2] = softplusf(sums[2] + a.bgam_w[0]) + 1.f;
        sc[3] = sqrtf(sums[12]);
        sc[4] = softplusf(sums[6] + a.bb_r[0]);
        sc[5] = sigmoidf(sums[7] + a.bg_r[0]);
        sc[6] = softplusf(sums[8] + a.bgam_r[0]) + 1.f;
        sc[7] = sqrtf(sums[13]);
        {
            const float v0 = sums[3] + a.bs_w[0], v1 = sums[4] + a.bs_w[1], v2 = sums[5] + a.bs_w[2];
            const float m = fmaxf(fmaxf(v0, v1), v2);
            const float e0 = __expf(v0 - m), e1 = __expf(v1 - m), e2 = __expf(v2 - m);
            const float s = e0 + e1 + e2;
            sc[8] = e0 / s; sc[9] = e1 / s; sc[10] = e2 / s;
        }
        sc[11] = sums[14];
        {
            const float v0 = sums[9] + a.bs_r[0], v1 = sums[10] + a.bs_r[1], v2 = sums[11] + a.bs_r[2];
            const float m = fmaxf(fmaxf(v0, v1), v2);
            const float e0 = __expf(v0 - m), e1 = __expf(v1 - m), e2 = __expf(v2 - m);
            const float s = e0 + e1 + e2;
            sc[12] = e0 / s; sc[13] = e1 / s; sc[14] = e2 / s;
        }
        sc[15] = sums[15];
    }
}

// single streaming pass over mem: x_w (+per-block max), dr, c5, nq, e1, e2
__global__ __launch_bounds__(256) void k_pass1(const float* __restrict__ mem,
                                               float* __restrict__ ws) {
    __shared__ float red4[4];
    const int w    = (blockIdx.x * 256 + threadIdx.x) >> 6;   // wave 0..8191
    const int lane = threadIdx.x & 63;
    const int q = lane & 15, r = lane >> 4;
    const int wbase = w << 6;                                  // 64 rows per wave
    const int b = wbase >> 13;
    const float4 kw = *(const float4*)(ws + OFF_KW + (b << 6) + (q << 2));
    const float4 kr = *(const float4*)(ws + OFF_KR + (b << 6) + (q << 2));
    const float4 ev = *(const float4*)(ws + OFF_ER + (b << 6) + (q << 2));
    const float4 av = *(const float4*)(ws + OFF_AD + (b << 6) + (q << 2));
    float4 ekr; ekr.x = ev.x * kr.x; ekr.y = ev.y * kr.y; ekr.z = ev.z * kr.z; ekr.w = ev.w * kr.w;
    const float beta = ws[OFF_SC + b * 16 + 0];
    const float kn   = ws[OFF_SC + b * 16 + 3];

    float lmax = -1e30f;
    for (int it = 0; it < 16; ++it) {
        const int row = wbase + (it << 2) + r;
        const float4 m = *(const float4*)(mem + ((size_t)row << 6) + (q << 2));
        float dw, nq, dr, e1, e2, c5;
        {   // x
            const float mm = m.x * m.x, tt = mm * ev.x, ma = m.x * av.x;
            dw = m.x * kw.x; nq = mm; dr = m.x * kr.x;
            e1 = ma - tt; e2 = ev.x * (tt - 2.f * ma); c5 = m.x * ekr.x;
        }
        {   // y
            const float mm = m.y * m.y, tt = mm * ev.y, ma = m.y * av.y;
            dw = fmaf(m.y, kw.y, dw); nq += mm; dr = fmaf(m.y, kr.y, dr);
            e1 += ma - tt; e2 = fmaf(ev.y, tt - 2.f * ma, e2); c5 = fmaf(m.y, ekr.y, c5);
        }
        {   // z
            const float mm = m.z * m.z, tt = mm * ev.z, ma = m.z * av.z;
            dw = fmaf(m.z, kw.z, dw); nq += mm; dr = fmaf(m.z, kr.z, dr);
            e1 += ma - tt; e2 = fmaf(ev.z, tt - 2.f * ma, e2); c5 = fmaf(m.z, ekr.z, c5);
        }
        {   // w
            const float mm = m.w * m.w, tt = mm * ev.w, ma = m.w * av.w;
            dw = fmaf(m.w, kw.w, dw); nq += mm; dr = fmaf(m.w, kr.w, dr);
            e1 += ma - tt; e2 = fmaf(ev.w, tt - 2.f * ma, e2); c5 = fmaf(m.w, ekr.w, c5);
        }
        #pragma unroll
        for (int mk = 8; mk >= 1; mk >>= 1) {
            dw += __shfl_xor(dw, mk); nq += __shfl_xor(nq, mk);
            dr += __shfl_xor(dr, mk); e1 += __shfl_xor(e1, mk);
            e2 += __shfl_xor(e2, mk); c5 += __shfl_xor(c5, mk);
        }
        const float xw = beta * dw / (sqrtf(nq) * kn + EPSF);
        lmax = fmaxf(lmax, xw);
        if (q == 0) {
            ws[OFF_XW + row] = xw; ws[OFF_DR + row] = dr; ws[OFF_C5 + row] = c5;
            ws[OFF_NQ + row] = nq; ws[OFF_E1 + row] = e1; ws[OFF_E2 + row] = e2;
        }
    }
    // per-block max of x_w
    lmax = fmaxf(lmax, __shfl_xor(lmax, 16));
    lmax = fmaxf(lmax, __shfl_xor(lmax, 32));
    if (lane == 0) red4[threadIdx.x >> 6] = lmax;
    __syncthreads();
    if (threadIdx.x == 0)
        ws[OFF_BM + blockIdx.x] = fmaxf(fmaxf(red4[0], red4[1]), fmaxf(red4[2], red4[3]));
}

// fused W+R addressing: one block (1024 thr) per batch; WW held in LDS between sides
__global__ __launch_bounds__(1024) void k_addrBoth(float* __restrict__ ws,
                                                   const float* __restrict__ prevw_w,
                                                   const float* __restrict__ prevw_r) {
    __shared__ float buf[Nn];
    __shared__ float red[16];
    const int b = blockIdx.x, t = threadIdx.x;
    const int bN = b * Nn;
    const float* sc = ws + OFF_SC + b * 16;
    const float g_w   = sc[1],  gam_w = sc[2];
    const float s0w = sc[8], s1w = sc[9], s2w = sc[10];
    const float beta_r = sc[4], g_r = sc[5], gam_r = sc[6], kn_r = sc[7];
    const float AK = sc[11], A2 = sc[15];
    const float s0r = sc[12], s1r = sc[13], s2r = sc[14];

    // ---------- W side ----------
    float M = -1e30f;
    for (int i = 0; i < 32; ++i) M = fmaxf(M, ws[OFF_BM + b * 32 + i]);

    float xs[8];
    float lsum = 0.f;
    #pragma unroll
    for (int i = 0; i < 8; ++i) {
        const int n = (i << 10) + t;
        const float e = __expf(ws[OFF_XW + bN + n] - M);
        xs[i] = e; lsum += e;
    }
    const float S = blockSum1024(lsum, red);
    const float sinv = 1.f / S;
    #pragma unroll
    for (int i = 0; i < 8; ++i) {
        const int n = (i << 10) + t;
        buf[n] = g_w * xs[i] * sinv + (1.f - g_w) * prevw_w[bN + n];
    }
    __syncthreads();
    float lps = 0.f;
    #pragma unroll
    for (int i = 0; i < 8; ++i) {
        const int n = (i << 10) + t;
        const float wsv = s0w * buf[(n + 1) & (Nn - 1)] + s1w * buf[n] + s2w * buf[(n - 1) & (Nn - 1)];
        const float wp = __expf(gam_w * __logf(wsv));
        xs[i] = wp; lps += wp;
    }
    const float PS = blockSum1024(lps, red);   // syncthreads inside guards buf reuse
    const float pinv = 1.f / (PS + EPSF);
    #pragma unroll
    for (int i = 0; i < 8; ++i) {
        const int n = (i << 10) + t;
        const float wwv = xs[i] * pinv;
        buf[n] = wwv;                            // keep for R side
        ws[OFF_WW + bN + n] = wwv;               // for k_read
    }
    __syncthreads();

    // ---------- R side ----------
    float lmax = -1e30f;
    #pragma unroll
    for (int i = 0; i < 8; ++i) {
        const int n = (i << 10) + t;
        const float w  = buf[n];
        const float d  = ws[OFF_DR + bN + n] + w * (AK - ws[OFF_C5 + bN + n]);
        float qq = ws[OFF_NQ + bN + n]
                 + 2.f * w * ws[OFF_E1 + bN + n]
                 + w * w * (ws[OFF_E2 + bN + n] + A2);
        qq = fmaxf(qq, 0.f);
        const float x = beta_r * d / (sqrtf(qq) * kn_r + EPSF);
        xs[i] = x; lmax = fmaxf(lmax, x);
    }
    const float Mr = blockMax1024(lmax, red);
    float lsr = 0.f;
    #pragma unroll
    for (int i = 0; i < 8; ++i) { const float e = __expf(xs[i] - Mr); xs[i] = e; lsr += e; }
    const float Sr = blockSum1024(lsr, red);
    const float srinv = 1.f / Sr;
    #pragma unroll
    for (int i = 0; i < 8; ++i) {
        const int n = (i << 10) + t;
        const float wgv = g_r * xs[i] * srinv + (1.f - g_r) * prevw_r[bN + n];
        xs[i] = wgv;
    }
    __syncthreads();                             // all buf (WW) reads done
    #pragma unroll
    for (int i = 0; i < 8; ++i) buf[(i << 10) + t] = xs[i];
    __syncthreads();
    float lpr = 0.f;
    #pragma unroll
    for (int i = 0; i < 8; ++i) {
        const int n = (i << 10) + t;
        const float wsv = s0r * buf[(n + 1) & (Nn - 1)] + s1r * buf[n] + s2r * buf[(n - 1) & (Nn - 1)];
        const float wp = __expf(gam_r * __logf(wsv));
        xs[i] = wp; lpr += wp;
    }
    const float PSr = blockSum1024(lpr, red);
    const float prinv = 1.f / (PSr + EPSF);
    #pragma unroll
    for (int i = 0; i < 8; ++i) ws[OFF_WR + bN + (i << 10) + t] = xs[i] * prinv;
}

// read-vector partials: recompute new_mem on the fly (second & last mem pass)
__global__ __launch_bounds__(256) void k_read(const float* __restrict__ mem,
                                              float* __restrict__ ws) {
    __shared__ float lds[4 * 64];
    const int b = blockIdx.x >> 5;
    const int chunk = blockIdx.x & 31;
    const int t = threadIdx.x;
    const int lane = t & 63, wv = t >> 6;
    const int q = lane & 15, r = lane >> 4;
    const float4 evv = *(const float4*)(ws + OFF_ER + (b << 6) + (q << 2));
    const float4 avv = *(const float4*)(ws + OFF_AD + (b << 6) + (q << 2));
    float a0 = 0.f, a1 = 0.f, a2 = 0.f, a3 = 0.f;
    const int base_n = chunk << 8;
    for (int gi = wv; gi < 64; gi += 4) {
        const int n = base_n + (gi << 2) + r;
        const int row = b * Nn + n;
        const float4 mv = *(const float4*)(mem + ((size_t)row << 6) + (q << 2));
        const float w   = ws[OFF_WW + row];
        const float wrv = ws[OFF_WR + row];
        a0 = fmaf((mv.x * (1.f - w * evv.x) + w * avv.x), wrv, a0);
        a1 = fmaf((mv.y * (1.f - w * evv.y) + w * avv.y), wrv, a1);
        a2 = fmaf((mv.z * (1.f - w * evv.z) + w * avv.z), wrv, a2);
        a3 = fmaf((mv.w * (1.f - w * evv.w) + w * avv.w), wrv, a3);
    }
    #pragma unroll
    for (int m = 16; m <= 32; m <<= 1) {
        a0 += __shfl_xor(a0, m); a1 += __shfl_xor(a1, m);
        a2 += __shfl_xor(a2, m); a3 += __shfl_xor(a3, m);
    }
    if (r == 0) {
        lds[wv * 64 + q * 4 + 0] = a0; lds[wv * 64 + q * 4 + 1] = a1;
        lds[wv * 64 + q * 4 + 2] = a2; lds[wv * 64 + q * 4 + 3] = a3;
    }
    __syncthreads();
    if (t < 64) {
        ws[OFF_PT + blockIdx.x * 64 + t] = lds[t] + lds[64 + t] + lds[128 + t] + lds[192 + t];
    }
}

__global__ __launch_bounds__(64) void k_reduce(const float* __restrict__ ws,
                                               float* __restrict__ out) {
    const int b = blockIdx.x, d = threadIdx.x;
    float s = 0.f;
    for (int i = 0; i < 32; ++i) s += ws[OFF_PT + ((b << 5) + i) * 64 + d];
    out[b * OUTW + 256 + d] = s;
}

extern "C" void kernel_launch(void* const* d_in, const int* in_sizes, int n_in,
                              void* d_out, int out_size, void* d_ws, size_t ws_size,
                              hipStream_t stream) {
    const float* x      = (const float*)d_in[0];
    const float* mem    = (const float*)d_in[1];
    const float* prw_r  = (const float*)d_in[2];
    const float* prw_w  = (const float*)d_in[3];
    const float* prv    = (const float*)d_in[4];

    float* ws  = (float*)d_ws;
    float* out = (float*)d_out;

    SetupArgs a;
    a.x = x; a.prv = prv;
    a.Wc = (const float*)d_in[5];  a.bc = (const float*)d_in[6];
    a.Wk_r = (const float*)d_in[7];  a.bk_r = (const float*)d_in[8];
    a.Wb_r = (const float*)d_in[9];  a.bb_r = (const float*)d_in[10];
    a.Wg_r = (const float*)d_in[11]; a.bg_r = (const float*)d_in[12];
    a.Ws_r = (const float*)d_in[13]; a.bs_r = (const float*)d_in[14];
    a.Wgam_r = (const float*)d_in[15]; a.bgam_r = (const float*)d_in[16];
    a.Wk_w = (const float*)d_in[17]; a.bk_w = (const float*)d_in[18];
    a.Wb_w = (const float*)d_in[19]; a.bb_w = (const float*)d_in[20];
    a.Wg_w = (const float*)d_in[21]; a.bg_w = (const float*)d_in[22];
    a.Ws_w = (const float*)d_in[23]; a.bs_w = (const float*)d_in[24];
    a.Wgam_w = (const float*)d_in[25]; a.bgam_w = (const float*)d_in[26];
    a.We_w = (const float*)d_in[27]; a.be_w = (const float*)d_in[28];
    a.Wa_w = (const float*)d_in[29]; a.ba_w = (const float*)d_in[30];
    a.ws = ws; a.out = out;

    k_setup<<<Bb, 256, 0, stream>>>(a);
    k_pass1<<<2048, 256, 0, stream>>>(mem, ws);
    k_addrBoth<<<Bb, 1024, 0, stream>>>(ws, prw_w, prw_r);
    k_read<<<Bb * 32, 256, 0, stream>>>(mem, ws);
    k_reduce<<<Bb, 64, 0, stream>>>(ws, out);
}